// Round 1
// 226.811 us; speedup vs baseline: 1.0011x; 1.0011x over previous
//
#include <hip/hip_runtime.h>
#include <math.h>

#define B     4096
#define ND    13
#define NS    26
#define NF    39
#define VOCAB 100000
#define NP    351      // l<=m pairs in 26x26
#define NPP   360      // padded to 8 chunks * 45
#define CHP   45       // p's per chunk (8 chunks: 4 waves x 2 half-waves)
#define GSTR  28       // Gst row: [0..25]=Gs_j, [26]=A1s, [27]=lut bits
#define RPB   4
#define XSS   212

// ---------------- workspace layout (floats) ----------------
#define OFF_GST 0        // 360*28 = 10080
#define OFF_CST 10080    // 1
#define OFF_C2J 10088    // 26

// ---- single merged precompute kernel, 28 independent blocks ----
__global__ __launch_bounds__(256) void k_pre(const float* __restrict__ W0,
                                             const float* __restrict__ W1,
                                             const float* __restrict__ b0,
                                             const float* __restrict__ b1,
                                             const float* __restrict__ clw,
                                             float* __restrict__ Gst,
                                             float* __restrict__ cst,
                                             float* __restrict__ c2j) {
    int blk = blockIdx.x, tid = threadIdx.x;
    if (blk < 26) {
        // block j: v[:,j] in LDS, then Gst[p][j] for all p, plus c2j[j]
        int j = blk;
        __shared__ float vh[2][128];
        __shared__ float vj[128];
        __shared__ float c2r[2];
        {
            int i = tid & 127, h = tid >> 7;
            const float* wp = W1 + (long)(h * 64) * 3328 + i * 26 + j;
            float acc = 0.f;
#pragma unroll 8
            for (int o = 0; o < 64; o++) acc += clw[128 + h * 64 + o] * wp[o * 3328];
            vh[h][i] = acc;
        }
        __syncthreads();
        if (tid < 128) {
            float vv = vh[0][tid] + vh[1][tid];
            vj[tid] = vv;
            float c = vv * b0[tid];
            for (int off = 32; off; off >>= 1) c += __shfl_down(c, off, 64);
            if ((tid & 63) == 0) c2r[tid >> 6] = c;
        }
        __syncthreads();
        if (tid == 0) c2j[j] = c2r[0] + c2r[1];
        for (int p = tid; p < NPP; p += 256) {
            float g = 0.f;
            if (p < NP) {
                int l = 0, rem = p;
                while (rem >= NS - l) { rem -= NS - l; l++; }
                int m = l + rem;
                float sym = (l != m) ? 1.f : 0.f;
                const float* wa = W0 + l * 26 + m;
                const float* wb = W0 + m * 26 + l;
#pragma unroll 8
                for (int i = 0; i < 128; i++)
                    g += vj[i] * (wa[i * 676] + sym * wb[i * 676]);
            }
            Gst[p * GSTR + j] = g;
        }
    } else if (blk == 26) {
        // A1s (slot 26) + lut bits (slot 27)
        for (int p = tid; p < NPP; p += 256) {
            float a = 0.f; int lmbits = 0;
            if (p < NP) {
                int l = 0, rem = p;
                while (rem >= NS - l) { rem -= NS - l; l++; }
                int m = l + rem;
                float sym = (l != m) ? 1.f : 0.f;
                const float* wa = W0 + l * 26 + m;
                const float* wb = W0 + m * 26 + l;
#pragma unroll 8
                for (int o = 0; o < 128; o++)
                    a += clw[o] * (wa[o * 676] + sym * wb[o * 676]);
                lmbits = (l << 5) | m;
            }
            Gst[p * GSTR + 26] = a;
            Gst[p * GSTR + 27] = __int_as_float(lmbits);
        }
    } else {
        __shared__ float red[2];
        float c = 0.f;
        if (tid < 128) {
            c = clw[tid] * b0[tid] + clw[128 + tid] * b1[tid];
            for (int off = 32; off; off >>= 1) c += __shfl_down(c, off, 64);
            if ((tid & 63) == 0) red[tid >> 6] = c;
        }
        __syncthreads();
        if (tid == 0) cst[0] = 8.f * (red[0] + red[1]);
    }
}

// ---- fused main: gather + linear + CIN (t-form, 27 accs) + DNN, 4 rows/block ----
// DNN phases restructured: split-K thread groups, float4 (b128) weight loads,
// 4-output x 4-row register tiles -> ~4x shorter L2-latency chains per wave.
__global__ __launch_bounds__(256, 4) void k_main(
    const float* __restrict__ inputs, const float* __restrict__ tables,
    const float* __restrict__ lW, const float* __restrict__ lb,
    const float* __restrict__ Gst, const float* __restrict__ c2j,
    const float* __restrict__ cst,
    const float* __restrict__ dW1, const float* __restrict__ db1,
    const float* __restrict__ dW2, const float* __restrict__ db2,
    const float* __restrict__ dW3, const float* __restrict__ db3,
    const float* __restrict__ dW4, const float* __restrict__ db4,
    const float* __restrict__ clb,
    float* __restrict__ out) {
    __shared__ float insf[RPB][40];
    __shared__ float xs[RPB][XSS];       // emb per row, CIN layout
    __shared__ float inT[256][RPB];      // DNN input transposed (row r per col)
    __shared__ float h1T[256][RPB];
    __shared__ float h2T[128][RPB];
    __shared__ float4 pbuf4[1024];       // split-K partials (16 KB), reused per layer
    __shared__ float lin_s[RPB], scin_s[RPB];
    __shared__ float redbuf[4][RPB];

    int tid = threadIdx.x;
    int b0r = blockIdx.x * RPB;

    // phase 1: raw inputs
    for (int t = tid; t < RPB * NF; t += 256) {
        int r = t / NF, c = t - r * NF;
        insf[r][c] = inputs[(b0r + r) * NF + c];
    }
    __syncthreads();

    // phase 2a: gather embeddings into xs + linear term
    if (tid < RPB * NS) {
        int r = tid / NS, f = tid - r * NS;
        int idx = (int)insf[r][ND + f];
        const float4* src = (const float4*)(tables + ((long)f * VOCAB + idx) * 8);
        float4 a = src[0], b4 = src[1];
        float4* dst = (float4*)&xs[r][f * 8];
        dst[0] = a; dst[1] = b4;
    }
    if (tid >= 192 && tid < 192 + RPB) {
        int r = tid - 192;
        float acc = lb[0];
        for (int c = 0; c < NF; c++) acc += insf[r][c] * lW[c];
        lin_s[r] = acc;
    }
    __syncthreads();

    // phase 2b: build transposed DNN input coalesced (conflict-free), then CIN
    for (int e = tid; e < 221 * RPB; e += 256) {
        int c = e >> 2, r = e & 3;
        inT[c][r] = (c < ND) ? insf[r][c] : xs[r][c - ND];
    }

    // phase 3: CIN, t-form. lane=(pg,r,k); chunk = wave*2+pg owns 45 p's.
    {
        int lane = tid & 63, w = tid >> 6;
        int pg = lane >> 5;
        int r = (lane >> 3) & 3;
        int k = lane & 7;
        int chunk = w * 2 + pg;          // 0..7
        const float* xrow = &xs[r][0];
        float t[27];
#pragma unroll
        for (int j = 0; j < 27; j++) t[j] = 0.f;
        const float4* grow = (const float4*)(Gst + chunk * CHP * GSTR);
#pragma unroll 2
        for (int pi = 0; pi < CHP; pi++) {
            float4 g6 = grow[pi * 7 + 6];
            int lm = __float_as_int(g6.w);
            float q = xrow[(lm >> 5) * 8 + k] * xrow[(lm & 31) * 8 + k];
            float4 g0 = grow[pi * 7 + 0], g1 = grow[pi * 7 + 1];
            float4 g2 = grow[pi * 7 + 2], g3 = grow[pi * 7 + 3];
            float4 g4 = grow[pi * 7 + 4], g5 = grow[pi * 7 + 5];
            t[0]  += g0.x * q; t[1]  += g0.y * q; t[2]  += g0.z * q; t[3]  += g0.w * q;
            t[4]  += g1.x * q; t[5]  += g1.y * q; t[6]  += g1.z * q; t[7]  += g1.w * q;
            t[8]  += g2.x * q; t[9]  += g2.y * q; t[10] += g2.z * q; t[11] += g2.w * q;
            t[12] += g3.x * q; t[13] += g3.y * q; t[14] += g3.z * q; t[15] += g3.w * q;
            t[16] += g4.x * q; t[17] += g4.y * q; t[18] += g4.z * q; t[19] += g4.w * q;
            t[20] += g5.x * q; t[21] += g5.y * q; t[22] += g5.z * q; t[23] += g5.w * q;
            t[24] += g6.x * q; t[25] += g6.y * q; t[26] += g6.z * q;
        }
        float csel = (chunk == 0) ? 1.f : 0.f;
        float part = t[26];
#pragma unroll
        for (int j = 0; j < 26; j++) {
            float xv = xrow[j * 8 + k];
            part += (t[j] + csel * c2j[j]) * xv;
        }
        part += __shfl_xor(part, 1, 64);
        part += __shfl_xor(part, 2, 64);
        part += __shfl_xor(part, 4, 64);
        part += __shfl_xor(part, 32, 64);
        if ((lane & 39) == 0) redbuf[w][r] = part;   // k==0 && pg==0
    }
    __syncthreads();

    // phase 4: scin finalize + DNN layer1 (221 -> 256), split-K x4, b128 weights
    if (tid < RPB) {
        float s = cst[0];
        for (int w = 0; w < 4; w++) s += redbuf[w][tid];
        scin_s[tid] = s;
    }
    {
        int oq = tid & 63, cg = tid >> 6;            // wave w == cg
        int c0 = cg * 55 + (cg != 0);
        int c1 = (cg + 1) * 55 + 1;                  // cg0:[0,56) cg1:[56,111) cg2:[111,166) cg3:[166,221)
        float4 a0 = make_float4(0.f, 0.f, 0.f, 0.f);
        float4 a1 = make_float4(0.f, 0.f, 0.f, 0.f);
        float4 a2 = make_float4(0.f, 0.f, 0.f, 0.f);
        float4 a3 = make_float4(0.f, 0.f, 0.f, 0.f);
#pragma unroll 4
        for (int c = c0; c < c1; c++) {
            float4 wv = *(const float4*)&dW1[c * 256 + (oq << 2)];
            float4 iv = *(const float4*)&inT[c][0];
            a0.x += iv.x * wv.x; a0.y += iv.y * wv.x; a0.z += iv.z * wv.x; a0.w += iv.w * wv.x;
            a1.x += iv.x * wv.y; a1.y += iv.y * wv.y; a1.z += iv.z * wv.y; a1.w += iv.w * wv.y;
            a2.x += iv.x * wv.z; a2.y += iv.y * wv.z; a2.z += iv.z * wv.z; a2.w += iv.w * wv.z;
            a3.x += iv.x * wv.w; a3.y += iv.y * wv.w; a3.z += iv.z * wv.w; a3.w += iv.w * wv.w;
        }
        int pb = (cg << 8) + (oq << 2);              // swizzled slots: conflict-free
        pbuf4[pb + ((0 + oq) & 3)] = a0;
        pbuf4[pb + ((1 + oq) & 3)] = a1;
        pbuf4[pb + ((2 + oq) & 3)] = a2;
        pbuf4[pb + ((3 + oq) & 3)] = a3;
    }
    __syncthreads();
    {   // combine: o = tid
        int oq = tid >> 2, j = tid & 3;
        int base = (oq << 2) + ((j + oq) & 3);
        float4 p0 = pbuf4[base];
        float4 p1 = pbuf4[256 + base];
        float4 p2 = pbuf4[512 + base];
        float4 p3 = pbuf4[768 + base];
        float bb = db1[tid];
        float4 o0;
        o0.x = fmaxf(p0.x + p1.x + p2.x + p3.x + bb, 0.f);
        o0.y = fmaxf(p0.y + p1.y + p2.y + p3.y + bb, 0.f);
        o0.z = fmaxf(p0.z + p1.z + p2.z + p3.z + bb, 0.f);
        o0.w = fmaxf(p0.w + p1.w + p2.w + p3.w + bb, 0.f);
        *(float4*)&h1T[tid][0] = o0;
    }
    __syncthreads();

    // phase 5: layer2 (256 -> 128), split-K x8, b128 weights
    {
        int oq = tid & 31, cg = tid >> 5;
        int c0 = cg << 5;
        float4 a0 = make_float4(0.f, 0.f, 0.f, 0.f);
        float4 a1 = make_float4(0.f, 0.f, 0.f, 0.f);
        float4 a2 = make_float4(0.f, 0.f, 0.f, 0.f);
        float4 a3 = make_float4(0.f, 0.f, 0.f, 0.f);
#pragma unroll 4
        for (int cc = 0; cc < 32; cc++) {
            int c = c0 + cc;
            float4 wv = *(const float4*)&dW2[c * 128 + (oq << 2)];
            float4 iv = *(const float4*)&h1T[c][0];
            a0.x += iv.x * wv.x; a0.y += iv.y * wv.x; a0.z += iv.z * wv.x; a0.w += iv.w * wv.x;
            a1.x += iv.x * wv.y; a1.y += iv.y * wv.y; a1.z += iv.z * wv.y; a1.w += iv.w * wv.y;
            a2.x += iv.x * wv.z; a2.y += iv.y * wv.z; a2.z += iv.z * wv.z; a2.w += iv.w * wv.z;
            a3.x += iv.x * wv.w; a3.y += iv.y * wv.w; a3.z += iv.z * wv.w; a3.w += iv.w * wv.w;
        }
        int pb = (cg << 7) + (oq << 2);
        pbuf4[pb + ((0 + oq) & 3)] = a0;
        pbuf4[pb + ((1 + oq) & 3)] = a1;
        pbuf4[pb + ((2 + oq) & 3)] = a2;
        pbuf4[pb + ((3 + oq) & 3)] = a3;
    }
    __syncthreads();
    if (tid < 128) {
        int oq = tid >> 2, j = tid & 3;
        int base = (oq << 2) + ((j + oq) & 3);
        float sx = db2[tid], sy = sx, sz = sx, sw = sx;
#pragma unroll
        for (int cg = 0; cg < 8; cg++) {
            float4 pv = pbuf4[(cg << 7) + base];
            sx += pv.x; sy += pv.y; sz += pv.z; sw += pv.w;
        }
        float4 o0;
        o0.x = fmaxf(sx, 0.f); o0.y = fmaxf(sy, 0.f);
        o0.z = fmaxf(sz, 0.f); o0.w = fmaxf(sw, 0.f);
        *(float4*)&h2T[tid][0] = o0;
    }
    __syncthreads();

    // phase 6: layer3 (128 -> 64), split-K x16, b128 weights
    {
        int oq = tid & 15, cg = tid >> 4;
        int c0 = cg << 3;
        float4 a0 = make_float4(0.f, 0.f, 0.f, 0.f);
        float4 a1 = make_float4(0.f, 0.f, 0.f, 0.f);
        float4 a2 = make_float4(0.f, 0.f, 0.f, 0.f);
        float4 a3 = make_float4(0.f, 0.f, 0.f, 0.f);
#pragma unroll
        for (int cc = 0; cc < 8; cc++) {
            int c = c0 + cc;
            float4 wv = *(const float4*)&dW3[c * 64 + (oq << 2)];
            float4 iv = *(const float4*)&h2T[c][0];
            a0.x += iv.x * wv.x; a0.y += iv.y * wv.x; a0.z += iv.z * wv.x; a0.w += iv.w * wv.x;
            a1.x += iv.x * wv.y; a1.y += iv.y * wv.y; a1.z += iv.z * wv.y; a1.w += iv.w * wv.y;
            a2.x += iv.x * wv.z; a2.y += iv.y * wv.z; a2.z += iv.z * wv.z; a2.w += iv.w * wv.z;
            a3.x += iv.x * wv.w; a3.y += iv.y * wv.w; a3.z += iv.z * wv.w; a3.w += iv.w * wv.w;
        }
        int pb = (cg << 6) + (oq << 2);
        pbuf4[pb + ((0 + oq) & 3)] = a0;
        pbuf4[pb + ((1 + oq) & 3)] = a1;
        pbuf4[pb + ((2 + oq) & 3)] = a2;
        pbuf4[pb + ((3 + oq) & 3)] = a3;
    }
    __syncthreads();

    // phase 7: combine L3 + layer4 (64 -> 1) + final combine + sigmoid
    if (tid < 64) {
        int oq = tid >> 2, j = tid & 3;
        int base = (oq << 2) + ((j + oq) & 3);
        float s0 = 0.f, s1 = 0.f, s2 = 0.f, s3 = 0.f;
#pragma unroll
        for (int cg = 0; cg < 16; cg++) {
            float4 pv = pbuf4[(cg << 6) + base];
            s0 += pv.x; s1 += pv.y; s2 += pv.z; s3 += pv.w;
        }
        float b3 = db3[tid];
        float w4 = dW4[tid];
        s0 = fmaxf(s0 + b3, 0.f) * w4; s1 = fmaxf(s1 + b3, 0.f) * w4;
        s2 = fmaxf(s2 + b3, 0.f) * w4; s3 = fmaxf(s3 + b3, 0.f) * w4;
#pragma unroll
        for (int off = 1; off < 64; off <<= 1) {
            s0 += __shfl_xor(s0, off, 64);
            s1 += __shfl_xor(s1, off, 64);
            s2 += __shfl_xor(s2, off, 64);
            s3 += __shfl_xor(s3, off, 64);
        }
        if (tid == 0) {
            float sv[4] = { s0, s1, s2, s3 };
            float bb = db4[0], cb = clb[0];
#pragma unroll
            for (int r = 0; r < RPB; r++) {
                float dense = fmaxf(sv[r] + bb, 0.f);
                float cin = fmaxf(scin_s[r] + cb, 0.f);
                float x = lin_s[r] + cin + dense;
                out[b0r + r] = 1.f / (1.f + expf(-x));
            }
        }
    }
}

extern "C" void kernel_launch(void* const* d_in, const int* in_sizes, int n_in,
                              void* d_out, int out_size, void* d_ws, size_t ws_size,
                              hipStream_t stream) {
    const float* inputs = (const float*)d_in[0];
    const float* tables = (const float*)d_in[1];
    const float* lW     = (const float*)d_in[2];
    const float* lb     = (const float*)d_in[3];
    const float* W0     = (const float*)d_in[4];
    const float* b0     = (const float*)d_in[5];
    const float* W1c    = (const float*)d_in[6];
    const float* b1c    = (const float*)d_in[7];
    const float* clw    = (const float*)d_in[8];
    const float* clb    = (const float*)d_in[9];
    const float* dW1    = (const float*)d_in[10];
    const float* db1    = (const float*)d_in[11];
    const float* dW2    = (const float*)d_in[12];
    const float* db2    = (const float*)d_in[13];
    const float* dW3    = (const float*)d_in[14];
    const float* db3    = (const float*)d_in[15];
    const float* dW4    = (const float*)d_in[16];
    const float* db4    = (const float*)d_in[17];

    float* ws   = (float*)d_ws;
    float* Gst  = ws + OFF_GST;
    float* cst  = ws + OFF_CST;
    float* c2j  = ws + OFF_C2J;

    k_pre<<<28, 256, 0, stream>>>(W0, W1c, b0, b1c, clw, Gst, cst, c2j);
    k_main<<<B / RPB, 256, 0, stream>>>(inputs, tables, lW, lb, Gst, c2j, cst,
                                        dW1, db1, dW2, db2, dW3, db3, dW4, db4, clb,
                                        (float*)d_out);
}

// Round 2
// 214.691 us; speedup vs baseline: 1.0576x; 1.0565x over previous
//
#include <hip/hip_runtime.h>
#include <math.h>

#define B     4096
#define ND    13
#define NS    26
#define NF    39
#define VOCAB 100000
#define NP    351      // l<=m pairs in 26x26
#define NPP   360      // padded to 8 chunks * 45
#define CHP   45       // p's per chunk (8 chunks: 1 wave each)
#define GSTR  28       // Gst row: [0..25]=Gs_j, [26]=A1s, [27]=lut bits
#define RPB   16
#define TPB   512
#define XSS   212

// ---------------- workspace layout (floats) ----------------
#define OFF_GST 0        // 360*28 = 10080
#define OFF_CST 10080    // 1
#define OFF_C2J 10088    // 26

// ---- single merged precompute kernel, 28 independent blocks ----
__global__ __launch_bounds__(256) void k_pre(const float* __restrict__ W0,
                                             const float* __restrict__ W1,
                                             const float* __restrict__ b0,
                                             const float* __restrict__ b1,
                                             const float* __restrict__ clw,
                                             float* __restrict__ Gst,
                                             float* __restrict__ cst,
                                             float* __restrict__ c2j) {
    int blk = blockIdx.x, tid = threadIdx.x;
    if (blk < 26) {
        int j = blk;
        __shared__ float vh[2][128];
        __shared__ float vj[128];
        __shared__ float c2r[2];
        {
            int i = tid & 127, h = tid >> 7;
            const float* wp = W1 + (long)(h * 64) * 3328 + i * 26 + j;
            float acc = 0.f;
#pragma unroll 8
            for (int o = 0; o < 64; o++) acc += clw[128 + h * 64 + o] * wp[o * 3328];
            vh[h][i] = acc;
        }
        __syncthreads();
        if (tid < 128) {
            float vv = vh[0][tid] + vh[1][tid];
            vj[tid] = vv;
            float c = vv * b0[tid];
            for (int off = 32; off; off >>= 1) c += __shfl_down(c, off, 64);
            if ((tid & 63) == 0) c2r[tid >> 6] = c;
        }
        __syncthreads();
        if (tid == 0) c2j[j] = c2r[0] + c2r[1];
        for (int p = tid; p < NPP; p += 256) {
            float g = 0.f;
            if (p < NP) {
                int l = 0, rem = p;
                while (rem >= NS - l) { rem -= NS - l; l++; }
                int m = l + rem;
                float sym = (l != m) ? 1.f : 0.f;
                const float* wa = W0 + l * 26 + m;
                const float* wb = W0 + m * 26 + l;
#pragma unroll 8
                for (int i = 0; i < 128; i++)
                    g += vj[i] * (wa[i * 676] + sym * wb[i * 676]);
            }
            Gst[p * GSTR + j] = g;
        }
    } else if (blk == 26) {
        for (int p = tid; p < NPP; p += 256) {
            float a = 0.f; int lmbits = 0;
            if (p < NP) {
                int l = 0, rem = p;
                while (rem >= NS - l) { rem -= NS - l; l++; }
                int m = l + rem;
                float sym = (l != m) ? 1.f : 0.f;
                const float* wa = W0 + l * 26 + m;
                const float* wb = W0 + m * 26 + l;
#pragma unroll 8
                for (int o = 0; o < 128; o++)
                    a += clw[o] * (wa[o * 676] + sym * wb[o * 676]);
                lmbits = (l << 5) | m;
            }
            Gst[p * GSTR + 26] = a;
            Gst[p * GSTR + 27] = __int_as_float(lmbits);
        }
    } else {
        __shared__ float red[2];
        float c = 0.f;
        if (tid < 128) {
            c = clw[tid] * b0[tid] + clw[128 + tid] * b1[tid];
            for (int off = 32; off; off >>= 1) c += __shfl_down(c, off, 64);
            if ((tid & 63) == 0) red[tid >> 6] = c;
        }
        __syncthreads();
        if (tid == 0) cst[0] = 8.f * (red[0] + red[1]);
    }
}

// ---- fused main: 16 rows/block, 512 threads, 1 block/CU ----
// L2 traffic cut 4x vs RPB=4: each 1KB weight row read once per 16 rows.
// Gst staged to LDS once per block; CIN reads are LDS broadcast.
__global__ __launch_bounds__(512, 2) void k_main(
    const float* __restrict__ inputs, const float* __restrict__ tables,
    const float* __restrict__ lW, const float* __restrict__ lb,
    const float* __restrict__ Gst, const float* __restrict__ c2j,
    const float* __restrict__ cst,
    const float* __restrict__ dW1, const float* __restrict__ db1,
    const float* __restrict__ dW2, const float* __restrict__ db2,
    const float* __restrict__ dW3, const float* __restrict__ db3,
    const float* __restrict__ dW4, const float* __restrict__ db4,
    const float* __restrict__ clb,
    float* __restrict__ out) {
    __shared__ float4 sGst4[NPP * 7];        // 2520 float4 = 40320 B
    __shared__ float insf[RPB][40];
    __shared__ float xs[RPB][XSS];           // emb per row, CIN layout
    __shared__ float inT[221][RPB];          // DNN input transposed [c][r]
    __shared__ float h1T[256][RPB];
    __shared__ float h2T[128][RPB];
    __shared__ float4 pbuf4[2048];           // split-K partials (32 KB)
    __shared__ float lin_s[RPB], scin_s[RPB];
    __shared__ float redbuf[8][RPB];
    __shared__ float c2s[26];

    int tid = threadIdx.x;
    int b0r = blockIdx.x * RPB;

    // phase 0: stage Gst + c2j to LDS, load raw inputs
    for (int i = tid; i < NPP * 7; i += TPB) sGst4[i] = ((const float4*)Gst)[i];
    if (tid < 26) c2s[tid] = c2j[tid];
    for (int e = tid; e < RPB * NF; e += TPB) {
        int r = e / NF, c = e - r * NF;
        insf[r][c] = inputs[(b0r + r) * NF + c];
    }
    __syncthreads();

    // phase 1: gather embeddings + linear term
    if (tid < RPB * NS) {
        int r = tid / NS, f = tid - r * NS;
        int idx = (int)insf[r][ND + f];
        const float4* src = (const float4*)(tables + ((long)f * VOCAB + idx) * 8);
        float4 a = src[0], b4 = src[1];
        float4* dst = (float4*)&xs[r][f * 8];
        dst[0] = a; dst[1] = b4;
    }
    if (tid >= 448 && tid < 448 + RPB) {
        int r = tid - 448;
        float acc = lb[0];
        for (int c = 0; c < NF; c++) acc += insf[r][c] * lW[c];
        lin_s[r] = acc;
    }
    __syncthreads();

    // phase 2: build transposed DNN input (coalesced, conflict-free)
    for (int e = tid; e < 221 * RPB; e += TPB) {
        int c = e >> 4, r = e & 15;
        inT[c][r] = (c < ND) ? insf[r][c] : xs[r][c - ND];
    }

    // phase 3: CIN. wave = chunk (8 waves, 8 chunks); lane=(rlo,k); 2 row passes.
    {
        int lane = tid & 63, w = tid >> 6;
        int rlo = lane >> 3, k = lane & 7;
        const float4* grow = &sGst4[w * CHP * 7];
        float csel = (w == 0) ? 1.f : 0.f;
#pragma unroll 1
        for (int h = 0; h < 2; h++) {
            int row = (h << 3) + rlo;
            const float* xrow = &xs[row][0];
            float t[27];
#pragma unroll
            for (int j = 0; j < 27; j++) t[j] = 0.f;
#pragma unroll 2
            for (int pi = 0; pi < CHP; pi++) {
                float4 g6 = grow[pi * 7 + 6];
                int lm = __float_as_int(g6.w);
                float q = xrow[(lm >> 5) * 8 + k] * xrow[(lm & 31) * 8 + k];
                float4 g0 = grow[pi * 7 + 0], g1 = grow[pi * 7 + 1];
                float4 g2 = grow[pi * 7 + 2], g3 = grow[pi * 7 + 3];
                float4 g4 = grow[pi * 7 + 4], g5 = grow[pi * 7 + 5];
                t[0]  += g0.x * q; t[1]  += g0.y * q; t[2]  += g0.z * q; t[3]  += g0.w * q;
                t[4]  += g1.x * q; t[5]  += g1.y * q; t[6]  += g1.z * q; t[7]  += g1.w * q;
                t[8]  += g2.x * q; t[9]  += g2.y * q; t[10] += g2.z * q; t[11] += g2.w * q;
                t[12] += g3.x * q; t[13] += g3.y * q; t[14] += g3.z * q; t[15] += g3.w * q;
                t[16] += g4.x * q; t[17] += g4.y * q; t[18] += g4.z * q; t[19] += g4.w * q;
                t[20] += g5.x * q; t[21] += g5.y * q; t[22] += g5.z * q; t[23] += g5.w * q;
                t[24] += g6.x * q; t[25] += g6.y * q; t[26] += g6.z * q;
            }
            float part = t[26];
#pragma unroll
            for (int j = 0; j < 26; j++) {
                float xv = xrow[j * 8 + k];
                part += (t[j] + csel * c2s[j]) * xv;
            }
            part += __shfl_xor(part, 1, 64);
            part += __shfl_xor(part, 2, 64);
            part += __shfl_xor(part, 4, 64);
            if (k == 0) redbuf[w][row] = part;
        }
    }
    __syncthreads();

    // phase 4: scin finalize + layer1 (221 -> 256), split-K x2, 16-row tiles
    if (tid < RPB) {
        float s = cst[0];
#pragma unroll
        for (int w = 0; w < 8; w++) s += redbuf[w][tid];
        scin_s[tid] = s;
    }
    {
        int o = tid & 255, cg = tid >> 8;
        int c0 = cg ? 111 : 0;
        int c1 = cg ? 221 : 111;
        float4 A0 = make_float4(0.f, 0.f, 0.f, 0.f);
        float4 A1 = A0, A2 = A0, A3 = A0;
#pragma unroll 4
        for (int c = c0; c < c1; c++) {
            float wv = dW1[c * 256 + o];
            const float4* ivp = (const float4*)&inT[c][0];
            float4 i0 = ivp[0], i1 = ivp[1], i2 = ivp[2], i3 = ivp[3];
            A0.x += i0.x * wv; A0.y += i0.y * wv; A0.z += i0.z * wv; A0.w += i0.w * wv;
            A1.x += i1.x * wv; A1.y += i1.y * wv; A1.z += i1.z * wv; A1.w += i1.w * wv;
            A2.x += i2.x * wv; A2.y += i2.y * wv; A2.z += i2.z * wv; A2.w += i2.w * wv;
            A3.x += i3.x * wv; A3.y += i3.y * wv; A3.z += i3.z * wv; A3.w += i3.w * wv;
        }
        int pb = (cg << 10) + (o << 2);
        pbuf4[pb + ((0 + o) & 3)] = A0;
        pbuf4[pb + ((1 + o) & 3)] = A1;
        pbuf4[pb + ((2 + o) & 3)] = A2;
        pbuf4[pb + ((3 + o) & 3)] = A3;
    }
    __syncthreads();
    if (tid < 256) {
        int o = tid, base = o << 2;
        float bb = db1[o];
        float4 S0, S1, S2, S3;
        {
            int s = (0 + o) & 3;
            float4 p = pbuf4[base + s], q = pbuf4[1024 + base + s];
            S0.x = fmaxf(p.x + q.x + bb, 0.f); S0.y = fmaxf(p.y + q.y + bb, 0.f);
            S0.z = fmaxf(p.z + q.z + bb, 0.f); S0.w = fmaxf(p.w + q.w + bb, 0.f);
        }
        {
            int s = (1 + o) & 3;
            float4 p = pbuf4[base + s], q = pbuf4[1024 + base + s];
            S1.x = fmaxf(p.x + q.x + bb, 0.f); S1.y = fmaxf(p.y + q.y + bb, 0.f);
            S1.z = fmaxf(p.z + q.z + bb, 0.f); S1.w = fmaxf(p.w + q.w + bb, 0.f);
        }
        {
            int s = (2 + o) & 3;
            float4 p = pbuf4[base + s], q = pbuf4[1024 + base + s];
            S2.x = fmaxf(p.x + q.x + bb, 0.f); S2.y = fmaxf(p.y + q.y + bb, 0.f);
            S2.z = fmaxf(p.z + q.z + bb, 0.f); S2.w = fmaxf(p.w + q.w + bb, 0.f);
        }
        {
            int s = (3 + o) & 3;
            float4 p = pbuf4[base + s], q = pbuf4[1024 + base + s];
            S3.x = fmaxf(p.x + q.x + bb, 0.f); S3.y = fmaxf(p.y + q.y + bb, 0.f);
            S3.z = fmaxf(p.z + q.z + bb, 0.f); S3.w = fmaxf(p.w + q.w + bb, 0.f);
        }
        *(float4*)&h1T[o][0]  = S0;
        *(float4*)&h1T[o][4]  = S1;
        *(float4*)&h1T[o][8]  = S2;
        *(float4*)&h1T[o][12] = S3;
    }
    __syncthreads();

    // phase 5: layer2 (256 -> 128), split-K x4, 16-row tiles
    {
        int o = tid & 127, cg = tid >> 7;
        int c0 = cg << 6;
        float4 A0 = make_float4(0.f, 0.f, 0.f, 0.f);
        float4 A1 = A0, A2 = A0, A3 = A0;
#pragma unroll 4
        for (int cc = 0; cc < 64; cc++) {
            int c = c0 + cc;
            float wv = dW2[c * 128 + o];
            const float4* ivp = (const float4*)&h1T[c][0];
            float4 i0 = ivp[0], i1 = ivp[1], i2 = ivp[2], i3 = ivp[3];
            A0.x += i0.x * wv; A0.y += i0.y * wv; A0.z += i0.z * wv; A0.w += i0.w * wv;
            A1.x += i1.x * wv; A1.y += i1.y * wv; A1.z += i1.z * wv; A1.w += i1.w * wv;
            A2.x += i2.x * wv; A2.y += i2.y * wv; A2.z += i2.z * wv; A2.w += i2.w * wv;
            A3.x += i3.x * wv; A3.y += i3.y * wv; A3.z += i3.z * wv; A3.w += i3.w * wv;
        }
        int pb = (cg << 9) + (o << 2);
        pbuf4[pb + ((0 + o) & 3)] = A0;
        pbuf4[pb + ((1 + o) & 3)] = A1;
        pbuf4[pb + ((2 + o) & 3)] = A2;
        pbuf4[pb + ((3 + o) & 3)] = A3;
    }
    __syncthreads();
    if (tid < 128) {
        int o = tid, base = o << 2;
        float bb = db2[o];
        float4 S[4];
#pragma unroll
        for (int j = 0; j < 4; j++) {
            int s = (j + o) & 3;
            float sx = bb, sy = bb, sz = bb, sw = bb;
#pragma unroll
            for (int cg = 0; cg < 4; cg++) {
                float4 pv = pbuf4[(cg << 9) + base + s];
                sx += pv.x; sy += pv.y; sz += pv.z; sw += pv.w;
            }
            S[j].x = fmaxf(sx, 0.f); S[j].y = fmaxf(sy, 0.f);
            S[j].z = fmaxf(sz, 0.f); S[j].w = fmaxf(sw, 0.f);
        }
        *(float4*)&h2T[o][0]  = S[0];
        *(float4*)&h2T[o][4]  = S[1];
        *(float4*)&h2T[o][8]  = S[2];
        *(float4*)&h2T[o][12] = S[3];
    }
    __syncthreads();

    // phase 6: layer3 (128 -> 64), split-K x8, 16-row tiles
    {
        int o = tid & 63, cg = tid >> 6;
        int c0 = cg << 4;
        float4 A0 = make_float4(0.f, 0.f, 0.f, 0.f);
        float4 A1 = A0, A2 = A0, A3 = A0;
#pragma unroll
        for (int cc = 0; cc < 16; cc++) {
            int c = c0 + cc;
            float wv = dW3[c * 64 + o];
            const float4* ivp = (const float4*)&h2T[c][0];
            float4 i0 = ivp[0], i1 = ivp[1], i2 = ivp[2], i3 = ivp[3];
            A0.x += i0.x * wv; A0.y += i0.y * wv; A0.z += i0.z * wv; A0.w += i0.w * wv;
            A1.x += i1.x * wv; A1.y += i1.y * wv; A1.z += i1.z * wv; A1.w += i1.w * wv;
            A2.x += i2.x * wv; A2.y += i2.y * wv; A2.z += i2.z * wv; A2.w += i2.w * wv;
            A3.x += i3.x * wv; A3.y += i3.y * wv; A3.z += i3.z * wv; A3.w += i3.w * wv;
        }
        int pb = (cg << 8) + (o << 2);
        pbuf4[pb + ((0 + o) & 3)] = A0;
        pbuf4[pb + ((1 + o) & 3)] = A1;
        pbuf4[pb + ((2 + o) & 3)] = A2;
        pbuf4[pb + ((3 + o) & 3)] = A3;
    }
    __syncthreads();

    // phase 7: combine L3 + layer4 (64 -> 1) + final combine + sigmoid
    if (tid < 64) {
        int o = tid, base = o << 2;
        float4 S0 = make_float4(0.f, 0.f, 0.f, 0.f);
        float4 S1 = S0, S2 = S0, S3 = S0;
#pragma unroll
        for (int cg = 0; cg < 8; cg++) {
            int pb = (cg << 8) + base;
            float4 p0 = pbuf4[pb + ((0 + o) & 3)];
            float4 p1 = pbuf4[pb + ((1 + o) & 3)];
            float4 p2 = pbuf4[pb + ((2 + o) & 3)];
            float4 p3 = pbuf4[pb + ((3 + o) & 3)];
            S0.x += p0.x; S0.y += p0.y; S0.z += p0.z; S0.w += p0.w;
            S1.x += p1.x; S1.y += p1.y; S1.z += p1.z; S1.w += p1.w;
            S2.x += p2.x; S2.y += p2.y; S2.z += p2.z; S2.w += p2.w;
            S3.x += p3.x; S3.y += p3.y; S3.z += p3.z; S3.w += p3.w;
        }
        float b3 = db3[o], w4 = dW4[o];
        S0.x = fmaxf(S0.x + b3, 0.f) * w4; S0.y = fmaxf(S0.y + b3, 0.f) * w4;
        S0.z = fmaxf(S0.z + b3, 0.f) * w4; S0.w = fmaxf(S0.w + b3, 0.f) * w4;
        S1.x = fmaxf(S1.x + b3, 0.f) * w4; S1.y = fmaxf(S1.y + b3, 0.f) * w4;
        S1.z = fmaxf(S1.z + b3, 0.f) * w4; S1.w = fmaxf(S1.w + b3, 0.f) * w4;
        S2.x = fmaxf(S2.x + b3, 0.f) * w4; S2.y = fmaxf(S2.y + b3, 0.f) * w4;
        S2.z = fmaxf(S2.z + b3, 0.f) * w4; S2.w = fmaxf(S2.w + b3, 0.f) * w4;
        S3.x = fmaxf(S3.x + b3, 0.f) * w4; S3.y = fmaxf(S3.y + b3, 0.f) * w4;
        S3.z = fmaxf(S3.z + b3, 0.f) * w4; S3.w = fmaxf(S3.w + b3, 0.f) * w4;
#pragma unroll
        for (int off = 1; off < 64; off <<= 1) {
            S0.x += __shfl_xor(S0.x, off, 64); S0.y += __shfl_xor(S0.y, off, 64);
            S0.z += __shfl_xor(S0.z, off, 64); S0.w += __shfl_xor(S0.w, off, 64);
            S1.x += __shfl_xor(S1.x, off, 64); S1.y += __shfl_xor(S1.y, off, 64);
            S1.z += __shfl_xor(S1.z, off, 64); S1.w += __shfl_xor(S1.w, off, 64);
            S2.x += __shfl_xor(S2.x, off, 64); S2.y += __shfl_xor(S2.y, off, 64);
            S2.z += __shfl_xor(S2.z, off, 64); S2.w += __shfl_xor(S2.w, off, 64);
            S3.x += __shfl_xor(S3.x, off, 64); S3.y += __shfl_xor(S3.y, off, 64);
            S3.z += __shfl_xor(S3.z, off, 64); S3.w += __shfl_xor(S3.w, off, 64);
        }
        if (tid == 0) {
            float sv[16] = { S0.x, S0.y, S0.z, S0.w, S1.x, S1.y, S1.z, S1.w,
                             S2.x, S2.y, S2.z, S2.w, S3.x, S3.y, S3.z, S3.w };
            float bb = db4[0], cb = clb[0];
#pragma unroll
            for (int r = 0; r < RPB; r++) {
                float dense = fmaxf(sv[r] + bb, 0.f);
                float cin = fmaxf(scin_s[r] + cb, 0.f);
                float x = lin_s[r] + cin + dense;
                out[b0r + r] = 1.f / (1.f + expf(-x));
            }
        }
    }
}

extern "C" void kernel_launch(void* const* d_in, const int* in_sizes, int n_in,
                              void* d_out, int out_size, void* d_ws, size_t ws_size,
                              hipStream_t stream) {
    const float* inputs = (const float*)d_in[0];
    const float* tables = (const float*)d_in[1];
    const float* lW     = (const float*)d_in[2];
    const float* lb     = (const float*)d_in[3];
    const float* W0     = (const float*)d_in[4];
    const float* b0     = (const float*)d_in[5];
    const float* W1c    = (const float*)d_in[6];
    const float* b1c    = (const float*)d_in[7];
    const float* clw    = (const float*)d_in[8];
    const float* clb    = (const float*)d_in[9];
    const float* dW1    = (const float*)d_in[10];
    const float* db1    = (const float*)d_in[11];
    const float* dW2    = (const float*)d_in[12];
    const float* db2    = (const float*)d_in[13];
    const float* dW3    = (const float*)d_in[14];
    const float* db3    = (const float*)d_in[15];
    const float* dW4    = (const float*)d_in[16];
    const float* db4    = (const float*)d_in[17];

    float* ws   = (float*)d_ws;
    float* Gst  = ws + OFF_GST;
    float* cst  = ws + OFF_CST;
    float* c2j  = ws + OFF_C2J;

    k_pre<<<28, 256, 0, stream>>>(W0, W1c, b0, b1c, clw, Gst, cst, c2j);
    k_main<<<B / RPB, TPB, 0, stream>>>(inputs, tables, lW, lb, Gst, c2j, cst,
                                        dW1, db1, dW2, db2, dW3, db3, dW4, db4, clb,
                                        (float*)d_out);
}

// Round 3
// 210.406 us; speedup vs baseline: 1.0791x; 1.0204x over previous
//
#include <hip/hip_runtime.h>
#include <math.h>

#define B     4096
#define ND    13
#define NS    26
#define NF    39
#define VOCAB 100000
#define NP    351      // l<=m pairs in 26x26
#define NPP   360      // padded to 8 chunks * 45
#define CHP   45       // p's per chunk (8 chunks: 1 wave each)
#define GSTR  28       // Gst row: [0..25]=Gs_j, [26]=A1s, [27]=lut bits
#define RPB   8
#define TPB   512
#define XSS   212

// ---------------- workspace layout (floats) ----------------
#define OFF_GST 0        // 360*28 = 10080
#define OFF_CST 10080    // 1
#define OFF_C2J 10088    // 26

// ---- single merged precompute kernel, 28 independent blocks ----
__global__ __launch_bounds__(256) void k_pre(const float* __restrict__ W0,
                                             const float* __restrict__ W1,
                                             const float* __restrict__ b0,
                                             const float* __restrict__ b1,
                                             const float* __restrict__ clw,
                                             float* __restrict__ Gst,
                                             float* __restrict__ cst,
                                             float* __restrict__ c2j) {
    int blk = blockIdx.x, tid = threadIdx.x;
    if (blk < 26) {
        int j = blk;
        __shared__ float vh[2][128];
        __shared__ float vj[128];
        __shared__ float c2r[2];
        {
            int i = tid & 127, h = tid >> 7;
            const float* wp = W1 + (long)(h * 64) * 3328 + i * 26 + j;
            float acc = 0.f;
#pragma unroll 8
            for (int o = 0; o < 64; o++) acc += clw[128 + h * 64 + o] * wp[o * 3328];
            vh[h][i] = acc;
        }
        __syncthreads();
        if (tid < 128) {
            float vv = vh[0][tid] + vh[1][tid];
            vj[tid] = vv;
            float c = vv * b0[tid];
            for (int off = 32; off; off >>= 1) c += __shfl_down(c, off, 64);
            if ((tid & 63) == 0) c2r[tid >> 6] = c;
        }
        __syncthreads();
        if (tid == 0) c2j[j] = c2r[0] + c2r[1];
        for (int p = tid; p < NPP; p += 256) {
            float g = 0.f;
            if (p < NP) {
                int l = 0, rem = p;
                while (rem >= NS - l) { rem -= NS - l; l++; }
                int m = l + rem;
                float sym = (l != m) ? 1.f : 0.f;
                const float* wa = W0 + l * 26 + m;
                const float* wb = W0 + m * 26 + l;
#pragma unroll 8
                for (int i = 0; i < 128; i++)
                    g += vj[i] * (wa[i * 676] + sym * wb[i * 676]);
            }
            Gst[p * GSTR + j] = g;
        }
    } else if (blk == 26) {
        for (int p = tid; p < NPP; p += 256) {
            float a = 0.f; int lmbits = 0;
            if (p < NP) {
                int l = 0, rem = p;
                while (rem >= NS - l) { rem -= NS - l; l++; }
                int m = l + rem;
                float sym = (l != m) ? 1.f : 0.f;
                const float* wa = W0 + l * 26 + m;
                const float* wb = W0 + m * 26 + l;
#pragma unroll 8
                for (int o = 0; o < 128; o++)
                    a += clw[o] * (wa[o * 676] + sym * wb[o * 676]);
                lmbits = (l << 5) | m;
            }
            Gst[p * GSTR + 26] = a;
            Gst[p * GSTR + 27] = __int_as_float(lmbits);
        }
    } else {
        __shared__ float red[2];
        float c = 0.f;
        if (tid < 128) {
            c = clw[tid] * b0[tid] + clw[128 + tid] * b1[tid];
            for (int off = 32; off; off >>= 1) c += __shfl_down(c, off, 64);
            if ((tid & 63) == 0) red[tid >> 6] = c;
        }
        __syncthreads();
        if (tid == 0) cst[0] = 8.f * (red[0] + red[1]);
    }
}

// ---- fused main: 8 rows/block, 512 threads, 2 blocks/CU (LDS ~56 KB) ----
// pbuf/h1T/h2T aliased into sGst4 region (dead after CIN) -> 16 waves/CU.
__global__ __launch_bounds__(512, 4) void k_main(
    const float* __restrict__ inputs, const float* __restrict__ tables,
    const float* __restrict__ lW, const float* __restrict__ lb,
    const float* __restrict__ Gst, const float* __restrict__ c2j,
    const float* __restrict__ cst,
    const float* __restrict__ dW1, const float* __restrict__ db1,
    const float* __restrict__ dW2, const float* __restrict__ db2,
    const float* __restrict__ dW3, const float* __restrict__ db3,
    const float* __restrict__ dW4, const float* __restrict__ db4,
    const float* __restrict__ clb,
    float* __restrict__ out) {
    __shared__ float4 sGst4[NPP * 7];        // 40320 B; aliased after CIN:
                                             //   pbuf4 = sGst4[0..1024)        (16 KB)
                                             //   h1T   = floats at sGst4+1024  (8 KB, [256][8])
                                             //   h2T   = floats at sGst4+1536  (4 KB, [128][8])
    __shared__ float insf[RPB][40];
    __shared__ float xs[RPB][XSS];           // emb per row, CIN layout
    __shared__ float inT[221][RPB];          // DNN input transposed [c][r]
    __shared__ float lin_s[RPB], scin_s[RPB];
    __shared__ float redbuf[8][RPB];
    __shared__ float c2s[26];

    float4* pbuf4 = sGst4;
    float*  h1T   = (float*)(sGst4 + 1024);
    float*  h2T   = (float*)(sGst4 + 1536);

    int tid = threadIdx.x;
    int b0r = blockIdx.x * RPB;

    // phase 0: stage Gst + c2j to LDS, load raw inputs
    for (int i = tid; i < NPP * 7; i += TPB) sGst4[i] = ((const float4*)Gst)[i];
    if (tid < 26) c2s[tid] = c2j[tid];
    for (int e = tid; e < RPB * NF; e += TPB) {
        int r = e / NF, c = e - r * NF;
        insf[r][c] = inputs[(b0r + r) * NF + c];
    }
    __syncthreads();

    // phase 1: gather embeddings + linear term
    if (tid < RPB * NS) {
        int r = tid / NS, f = tid - r * NS;
        int idx = (int)insf[r][ND + f];
        const float4* src = (const float4*)(tables + ((long)f * VOCAB + idx) * 8);
        float4 a = src[0], b4 = src[1];
        float4* dst = (float4*)&xs[r][f * 8];
        dst[0] = a; dst[1] = b4;
    }
    if (tid >= 448 && tid < 448 + RPB) {
        int r = tid - 448;
        float acc = lb[0];
        for (int c = 0; c < NF; c++) acc += insf[r][c] * lW[c];
        lin_s[r] = acc;
    }
    __syncthreads();

    // phase 2: build transposed DNN input (coalesced, conflict-free)
    for (int e = tid; e < 221 * RPB; e += TPB) {
        int c = e >> 3, r = e & 7;
        inT[c][r] = (c < ND) ? insf[r][c] : xs[r][c - ND];
    }

    // phase 3: CIN. wave = chunk (8 waves, 8 chunks); lane=(row,k); single pass.
    {
        int lane = tid & 63, w = tid >> 6;
        int row = lane >> 3, k = lane & 7;
        const float4* grow = &sGst4[w * CHP * 7];
        float csel = (w == 0) ? 1.f : 0.f;
        const float* xrow = &xs[row][0];
        float t[27];
#pragma unroll
        for (int j = 0; j < 27; j++) t[j] = 0.f;
#pragma unroll 2
        for (int pi = 0; pi < CHP; pi++) {
            float4 g6 = grow[pi * 7 + 6];
            int lm = __float_as_int(g6.w);
            float q = xrow[(lm >> 5) * 8 + k] * xrow[(lm & 31) * 8 + k];
            float4 g0 = grow[pi * 7 + 0], g1 = grow[pi * 7 + 1];
            float4 g2 = grow[pi * 7 + 2], g3 = grow[pi * 7 + 3];
            float4 g4 = grow[pi * 7 + 4], g5 = grow[pi * 7 + 5];
            t[0]  += g0.x * q; t[1]  += g0.y * q; t[2]  += g0.z * q; t[3]  += g0.w * q;
            t[4]  += g1.x * q; t[5]  += g1.y * q; t[6]  += g1.z * q; t[7]  += g1.w * q;
            t[8]  += g2.x * q; t[9]  += g2.y * q; t[10] += g2.z * q; t[11] += g2.w * q;
            t[12] += g3.x * q; t[13] += g3.y * q; t[14] += g3.z * q; t[15] += g3.w * q;
            t[16] += g4.x * q; t[17] += g4.y * q; t[18] += g4.z * q; t[19] += g4.w * q;
            t[20] += g5.x * q; t[21] += g5.y * q; t[22] += g5.z * q; t[23] += g5.w * q;
            t[24] += g6.x * q; t[25] += g6.y * q; t[26] += g6.z * q;
        }
        float part = t[26];
#pragma unroll
        for (int j = 0; j < 26; j++) {
            float xv = xrow[j * 8 + k];
            part += (t[j] + csel * c2s[j]) * xv;
        }
        part += __shfl_xor(part, 1, 64);
        part += __shfl_xor(part, 2, 64);
        part += __shfl_xor(part, 4, 64);
        if (k == 0) redbuf[w][row] = part;
    }
    __syncthreads();
    // sGst4 dead from here; region reused as pbuf4 / h1T / h2T.

    // phase 4: scin finalize + layer1 (221 -> 256), split-K x2, 8-row tiles
    if (tid < RPB) {
        float s = cst[0];
#pragma unroll
        for (int w = 0; w < 8; w++) s += redbuf[w][tid];
        scin_s[tid] = s;
    }
    {
        int o = tid & 255, cg = tid >> 8;
        int c0 = cg ? 111 : 0;
        int c1 = cg ? 221 : 111;
        float4 A0 = make_float4(0.f, 0.f, 0.f, 0.f);
        float4 A1 = A0;
#pragma unroll 4
        for (int c = c0; c < c1; c++) {
            float wv = dW1[c * 256 + o];
            const float4* ivp = (const float4*)&inT[c][0];
            float4 i0 = ivp[0], i1 = ivp[1];
            A0.x += i0.x * wv; A0.y += i0.y * wv; A0.z += i0.z * wv; A0.w += i0.w * wv;
            A1.x += i1.x * wv; A1.y += i1.y * wv; A1.z += i1.z * wv; A1.w += i1.w * wv;
        }
        // layout [cg][j][o]: lane-consecutive o -> conflict-free
        pbuf4[cg * 512 + 0 * 256 + o] = A0;
        pbuf4[cg * 512 + 1 * 256 + o] = A1;
    }
    __syncthreads();
    if (tid < 256) {
        int o = tid;
        float bb = db1[o];
        float4 p0 = pbuf4[o],       q0 = pbuf4[512 + o];
        float4 p1 = pbuf4[256 + o], q1 = pbuf4[768 + o];
        float4 S0, S1;
        S0.x = fmaxf(p0.x + q0.x + bb, 0.f); S0.y = fmaxf(p0.y + q0.y + bb, 0.f);
        S0.z = fmaxf(p0.z + q0.z + bb, 0.f); S0.w = fmaxf(p0.w + q0.w + bb, 0.f);
        S1.x = fmaxf(p1.x + q1.x + bb, 0.f); S1.y = fmaxf(p1.y + q1.y + bb, 0.f);
        S1.z = fmaxf(p1.z + q1.z + bb, 0.f); S1.w = fmaxf(p1.w + q1.w + bb, 0.f);
        *(float4*)&h1T[o * 8]     = S0;
        *(float4*)&h1T[o * 8 + 4] = S1;
    }
    __syncthreads();

    // phase 5: layer2 (256 -> 128), split-K x4, 8-row tiles
    {
        int o = tid & 127, cg = tid >> 7;
        int c0 = cg << 6;
        float4 A0 = make_float4(0.f, 0.f, 0.f, 0.f);
        float4 A1 = A0;
#pragma unroll 4
        for (int cc = 0; cc < 64; cc++) {
            int c = c0 + cc;
            float wv = dW2[c * 128 + o];
            const float4* ivp = (const float4*)&h1T[c * 8];
            float4 i0 = ivp[0], i1 = ivp[1];
            A0.x += i0.x * wv; A0.y += i0.y * wv; A0.z += i0.z * wv; A0.w += i0.w * wv;
            A1.x += i1.x * wv; A1.y += i1.y * wv; A1.z += i1.z * wv; A1.w += i1.w * wv;
        }
        pbuf4[cg * 256 + 0 * 128 + o] = A0;
        pbuf4[cg * 256 + 1 * 128 + o] = A1;
    }
    __syncthreads();
    if (tid < 128) {
        int o = tid;
        float bb = db2[o];
        float sx0 = bb, sy0 = bb, sz0 = bb, sw0 = bb;
        float sx1 = bb, sy1 = bb, sz1 = bb, sw1 = bb;
#pragma unroll
        for (int cg = 0; cg < 4; cg++) {
            float4 p0 = pbuf4[cg * 256 + o];
            float4 p1 = pbuf4[cg * 256 + 128 + o];
            sx0 += p0.x; sy0 += p0.y; sz0 += p0.z; sw0 += p0.w;
            sx1 += p1.x; sy1 += p1.y; sz1 += p1.z; sw1 += p1.w;
        }
        float4 S0, S1;
        S0.x = fmaxf(sx0, 0.f); S0.y = fmaxf(sy0, 0.f);
        S0.z = fmaxf(sz0, 0.f); S0.w = fmaxf(sw0, 0.f);
        S1.x = fmaxf(sx1, 0.f); S1.y = fmaxf(sy1, 0.f);
        S1.z = fmaxf(sz1, 0.f); S1.w = fmaxf(sw1, 0.f);
        *(float4*)&h2T[o * 8]     = S0;
        *(float4*)&h2T[o * 8 + 4] = S1;
    }
    __syncthreads();

    // phase 6: layer3 (128 -> 64), split-K x8, 8-row tiles
    {
        int o = tid & 63, cg = tid >> 6;
        int c0 = cg << 4;
        float4 A0 = make_float4(0.f, 0.f, 0.f, 0.f);
        float4 A1 = A0;
#pragma unroll 8
        for (int cc = 0; cc < 16; cc++) {
            int c = c0 + cc;
            float wv = dW3[c * 64 + o];
            const float4* ivp = (const float4*)&h2T[c * 8];
            float4 i0 = ivp[0], i1 = ivp[1];
            A0.x += i0.x * wv; A0.y += i0.y * wv; A0.z += i0.z * wv; A0.w += i0.w * wv;
            A1.x += i1.x * wv; A1.y += i1.y * wv; A1.z += i1.z * wv; A1.w += i1.w * wv;
        }
        pbuf4[cg * 128 + 0 * 64 + o] = A0;
        pbuf4[cg * 128 + 1 * 64 + o] = A1;
    }
    __syncthreads();

    // phase 7: combine L3 + layer4 (64 -> 1) + final combine + sigmoid
    if (tid < 64) {
        int o = tid;
        float4 S0 = make_float4(0.f, 0.f, 0.f, 0.f);
        float4 S1 = S0;
#pragma unroll
        for (int cg = 0; cg < 8; cg++) {
            float4 p0 = pbuf4[cg * 128 + o];
            float4 p1 = pbuf4[cg * 128 + 64 + o];
            S0.x += p0.x; S0.y += p0.y; S0.z += p0.z; S0.w += p0.w;
            S1.x += p1.x; S1.y += p1.y; S1.z += p1.z; S1.w += p1.w;
        }
        float b3 = db3[o], w4 = dW4[o];
        S0.x = fmaxf(S0.x + b3, 0.f) * w4; S0.y = fmaxf(S0.y + b3, 0.f) * w4;
        S0.z = fmaxf(S0.z + b3, 0.f) * w4; S0.w = fmaxf(S0.w + b3, 0.f) * w4;
        S1.x = fmaxf(S1.x + b3, 0.f) * w4; S1.y = fmaxf(S1.y + b3, 0.f) * w4;
        S1.z = fmaxf(S1.z + b3, 0.f) * w4; S1.w = fmaxf(S1.w + b3, 0.f) * w4;
#pragma unroll
        for (int off = 1; off < 64; off <<= 1) {
            S0.x += __shfl_xor(S0.x, off, 64); S0.y += __shfl_xor(S0.y, off, 64);
            S0.z += __shfl_xor(S0.z, off, 64); S0.w += __shfl_xor(S0.w, off, 64);
            S1.x += __shfl_xor(S1.x, off, 64); S1.y += __shfl_xor(S1.y, off, 64);
            S1.z += __shfl_xor(S1.z, off, 64); S1.w += __shfl_xor(S1.w, off, 64);
        }
        if (tid == 0) {
            float sv[8] = { S0.x, S0.y, S0.z, S0.w, S1.x, S1.y, S1.z, S1.w };
            float bb = db4[0], cb = clb[0];
#pragma unroll
            for (int r = 0; r < RPB; r++) {
                float dense = fmaxf(sv[r] + bb, 0.f);
                float cin = fmaxf(scin_s[r] + cb, 0.f);
                float x = lin_s[r] + cin + dense;
                out[b0r + r] = 1.f / (1.f + expf(-x));
            }
        }
    }
}

extern "C" void kernel_launch(void* const* d_in, const int* in_sizes, int n_in,
                              void* d_out, int out_size, void* d_ws, size_t ws_size,
                              hipStream_t stream) {
    const float* inputs = (const float*)d_in[0];
    const float* tables = (const float*)d_in[1];
    const float* lW     = (const float*)d_in[2];
    const float* lb     = (const float*)d_in[3];
    const float* W0     = (const float*)d_in[4];
    const float* b0     = (const float*)d_in[5];
    const float* W1c    = (const float*)d_in[6];
    const float* b1c    = (const float*)d_in[7];
    const float* clw    = (const float*)d_in[8];
    const float* clb    = (const float*)d_in[9];
    const float* dW1    = (const float*)d_in[10];
    const float* db1    = (const float*)d_in[11];
    const float* dW2    = (const float*)d_in[12];
    const float* db2    = (const float*)d_in[13];
    const float* dW3    = (const float*)d_in[14];
    const float* db3    = (const float*)d_in[15];
    const float* dW4    = (const float*)d_in[16];
    const float* db4    = (const float*)d_in[17];

    float* ws   = (float*)d_ws;
    float* Gst  = ws + OFF_GST;
    float* cst  = ws + OFF_CST;
    float* c2j  = ws + OFF_C2J;

    k_pre<<<28, 256, 0, stream>>>(W0, W1c, b0, b1c, clw, Gst, cst, c2j);
    k_main<<<B / RPB, TPB, 0, stream>>>(inputs, tables, lW, lb, Gst, c2j, cst,
                                        dW1, db1, dW2, db2, dW3, db3, dW4, db4, clb,
                                        (float*)d_out);
}

// Round 4
// 208.887 us; speedup vs baseline: 1.0870x; 1.0073x over previous
//
#include <hip/hip_runtime.h>
#include <math.h>

#define B     4096
#define ND    13
#define NS    26
#define NF    39
#define VOCAB 100000
#define NP    351      // l<=m pairs in 26x26
#define NPP   360      // padded to 8 chunks * 45
#define CHP   45       // p's per chunk (8 chunks: 1 wave each)
#define GSTR  28       // Gst row: [0..25]=Gs_j, [26]=A1s, [27]=lut bits
#define RPB   8
#define TPB   512
#define XSS   212

// ---------------- workspace layout (floats) ----------------
#define OFF_GST 0        // 360*28 = 10080
#define OFF_CST 10080    // 1
#define OFF_C2J 10088    // 26

// ---- single merged precompute kernel, 28 independent blocks ----
__global__ __launch_bounds__(256) void k_pre(const float* __restrict__ W0,
                                             const float* __restrict__ W1,
                                             const float* __restrict__ b0,
                                             const float* __restrict__ b1,
                                             const float* __restrict__ clw,
                                             float* __restrict__ Gst,
                                             float* __restrict__ cst,
                                             float* __restrict__ c2j) {
    int blk = blockIdx.x, tid = threadIdx.x;
    if (blk < 26) {
        int j = blk;
        __shared__ float vh[2][128];
        __shared__ float vj[128];
        __shared__ float c2r[2];
        {
            int i = tid & 127, h = tid >> 7;
            const float* wp = W1 + (long)(h * 64) * 3328 + i * 26 + j;
            float acc = 0.f;
#pragma unroll 8
            for (int o = 0; o < 64; o++) acc += clw[128 + h * 64 + o] * wp[o * 3328];
            vh[h][i] = acc;
        }
        __syncthreads();
        if (tid < 128) {
            float vv = vh[0][tid] + vh[1][tid];
            vj[tid] = vv;
            float c = vv * b0[tid];
            for (int off = 32; off; off >>= 1) c += __shfl_down(c, off, 64);
            if ((tid & 63) == 0) c2r[tid >> 6] = c;
        }
        __syncthreads();
        if (tid == 0) c2j[j] = c2r[0] + c2r[1];
        for (int p = tid; p < NPP; p += 256) {
            float g = 0.f;
            if (p < NP) {
                int l = 0, rem = p;
                while (rem >= NS - l) { rem -= NS - l; l++; }
                int m = l + rem;
                float sym = (l != m) ? 1.f : 0.f;
                const float* wa = W0 + l * 26 + m;
                const float* wb = W0 + m * 26 + l;
#pragma unroll 8
                for (int i = 0; i < 128; i++)
                    g += vj[i] * (wa[i * 676] + sym * wb[i * 676]);
            }
            Gst[p * GSTR + j] = g;
        }
    } else if (blk == 26) {
        for (int p = tid; p < NPP; p += 256) {
            float a = 0.f; int lmbits = 0;
            if (p < NP) {
                int l = 0, rem = p;
                while (rem >= NS - l) { rem -= NS - l; l++; }
                int m = l + rem;
                float sym = (l != m) ? 1.f : 0.f;
                const float* wa = W0 + l * 26 + m;
                const float* wb = W0 + m * 26 + l;
#pragma unroll 8
                for (int o = 0; o < 128; o++)
                    a += clw[o] * (wa[o * 676] + sym * wb[o * 676]);
                lmbits = (l << 5) | m;
            }
            Gst[p * GSTR + 26] = a;
            Gst[p * GSTR + 27] = __int_as_float(lmbits);
        }
    } else {
        __shared__ float red[2];
        float c = 0.f;
        if (tid < 128) {
            c = clw[tid] * b0[tid] + clw[128 + tid] * b1[tid];
            for (int off = 32; off; off >>= 1) c += __shfl_down(c, off, 64);
            if ((tid & 63) == 0) red[tid >> 6] = c;
        }
        __syncthreads();
        if (tid == 0) cst[0] = 8.f * (red[0] + red[1]);
    }
}

// ---- fused main: 8 rows/block, 512 threads ----
// CIN G-matrix read via wave-uniform scalar loads (SMEM/SGPR) -> no LDS staging.
// DNN: o-pair x 4-row register tiles, b64 weights, 1 LDS broadcast per 8 FMAs.
// pbuf thread-major contiguous (canonical conflict-free b128); h1T/h2T stride 12.
__global__ __launch_bounds__(512, 4) void k_main(
    const float* __restrict__ inputs, const float* __restrict__ tables,
    const float* __restrict__ lW, const float* __restrict__ lb,
    const float* __restrict__ Gst, const float* __restrict__ c2j,
    const float* __restrict__ cst,
    const float* __restrict__ dW1, const float* __restrict__ db1,
    const float* __restrict__ dW2, const float* __restrict__ db2,
    const float* __restrict__ dW3, const float* __restrict__ db3,
    const float* __restrict__ dW4, const float* __restrict__ db4,
    const float* __restrict__ clb,
    float* __restrict__ out) {
    __shared__ float insf[RPB][40];          // raw inputs
    __shared__ float xs[RPB][XSS];           // emb per row, CIN layout
    __shared__ float4 inT4[448];             // inT [221][8] floats (7168 B); h2T aliased here
    __shared__ float h1Tf[256 * 12];         // stride 12: bank-rotating, 16B-aligned
    __shared__ float4 pbuf4[1024];           // split-K partials, thread-major (16 KB)
    __shared__ float lin_s[RPB], scin_s[RPB];
    __shared__ float redbuf[8][RPB];

    float* inTf = (float*)inT4;              // [c*8 + r]
    float* h2Tf = (float*)inT4;              // [o*12 + ...] (alias; inT dead after L1 FMA)

    int tid = threadIdx.x;
    int b0r = blockIdx.x * RPB;

    // ---- phase 0: gather (issued first: HBM latency overlaps), insf, linear ----
    if (tid < RPB * NS) {                    // 208 threads
        int r = tid / NS, f = tid - r * NS;
        float fidx = inputs[(b0r + r) * NF + ND + f];
        int idx = (int)fidx;
        const float4* src = (const float4*)(tables + ((long)f * VOCAB + idx) * 8);
        float4 a = src[0], b4 = src[1];
        *(float4*)&xs[r][f * 8] = a;
        *(float4*)&xs[r][f * 8 + 4] = b4;
    }
    for (int e = tid; e < RPB * NF; e += TPB) {
        int r = e / NF, c = e - r * NF;
        insf[r][c] = inputs[(b0r + r) * NF + c];
    }
    if (tid >= 496 && tid < 496 + RPB) {     // linear term from global directly
        int r = tid - 496;
        float acc = lb[0];
        for (int c = 0; c < NF; c++) acc += inputs[(b0r + r) * NF + c] * lW[c];
        lin_s[r] = acc;
    }
    __syncthreads();

    // ---- phase 1: build transposed DNN input, then CIN ----
    for (int e = tid; e < 221 * RPB; e += TPB) {
        int c = e >> 3, r = e & 7;
        inTf[c * 8 + r] = (c < ND) ? insf[r][c] : xs[r][c - ND];
    }
    {
        int w = tid >> 6;
        int wu = __builtin_amdgcn_readfirstlane(w);      // force wave-uniform
        int lane = tid & 63;
        int row = lane >> 3, k = lane & 7;
        const float4* g4 = (const float4*)Gst + wu * CHP * 7;  // uniform -> s_load
        const float* xrow = &xs[row][0];
        float csel = (wu == 0) ? 1.f : 0.f;
        float t[27];
#pragma unroll
        for (int j = 0; j < 27; j++) t[j] = 0.f;
#pragma unroll 3
        for (int pi = 0; pi < CHP; pi++) {
            float4 g6 = g4[pi * 7 + 6];
            int lm = __float_as_int(g6.w);
            float q = xrow[(lm >> 5) * 8 + k] * xrow[(lm & 31) * 8 + k];
            float4 g0 = g4[pi * 7 + 0], g1 = g4[pi * 7 + 1];
            float4 g2 = g4[pi * 7 + 2], g3 = g4[pi * 7 + 3];
            float4 g4v = g4[pi * 7 + 4], g5 = g4[pi * 7 + 5];
            t[0]  += g0.x * q; t[1]  += g0.y * q; t[2]  += g0.z * q; t[3]  += g0.w * q;
            t[4]  += g1.x * q; t[5]  += g1.y * q; t[6]  += g1.z * q; t[7]  += g1.w * q;
            t[8]  += g2.x * q; t[9]  += g2.y * q; t[10] += g2.z * q; t[11] += g2.w * q;
            t[12] += g3.x * q; t[13] += g3.y * q; t[14] += g3.z * q; t[15] += g3.w * q;
            t[16] += g4v.x * q; t[17] += g4v.y * q; t[18] += g4v.z * q; t[19] += g4v.w * q;
            t[20] += g5.x * q; t[21] += g5.y * q; t[22] += g5.z * q; t[23] += g5.w * q;
            t[24] += g6.x * q; t[25] += g6.y * q; t[26] += g6.z * q;
        }
        float part = t[26];
#pragma unroll
        for (int j = 0; j < 26; j++) {
            float xv = xrow[j * 8 + k];
            part += (t[j] + csel * c2j[j]) * xv;   // c2j uniform -> s_load
        }
        part += __shfl_xor(part, 1, 64);
        part += __shfl_xor(part, 2, 64);
        part += __shfl_xor(part, 4, 64);
        if (k == 0) redbuf[w][row] = part;
    }
    __syncthreads();

    // ---- phase 2: layer1 FMA (221 -> 256), o-pair x 4-row tiles, split-K x2 ----
    {
        int p = tid & 127, h = (tid >> 7) & 1, cg = tid >> 8;
        int c0 = cg ? 111 : 0;
        int c1 = cg ? 221 : 111;
        float4 A0 = make_float4(0.f, 0.f, 0.f, 0.f);
        float4 A1 = A0;
#pragma unroll 4
        for (int c = c0; c < c1; c++) {
            float2 wv = *(const float2*)&dW1[c * 256 + 2 * p];
            float4 iv = *(const float4*)&inTf[c * 8 + 4 * h];
            A0.x += iv.x * wv.x; A0.y += iv.y * wv.x; A0.z += iv.z * wv.x; A0.w += iv.w * wv.x;
            A1.x += iv.x * wv.y; A1.y += iv.y * wv.y; A1.z += iv.z * wv.y; A1.w += iv.w * wv.y;
        }
        pbuf4[tid * 2]     = A0;
        pbuf4[tid * 2 + 1] = A1;
    }
    __syncthreads();
    // inT dead from here (h2Tf aliases its space, written in phase 5).

    // ---- phase 3: layer1 combine + relu -> h1T; scin finalize ----
    if (tid < 256) {
        int o = tid;
        float bb = db1[o];
        float4 a0 = pbuf4[o],       b0v = pbuf4[512 + o];   // h=0: rows 0-3, cg 0/1
        float4 a1 = pbuf4[256 + o], b1v = pbuf4[768 + o];   // h=1: rows 4-7
        float4 S0, S1;
        S0.x = fmaxf(a0.x + b0v.x + bb, 0.f); S0.y = fmaxf(a0.y + b0v.y + bb, 0.f);
        S0.z = fmaxf(a0.z + b0v.z + bb, 0.f); S0.w = fmaxf(a0.w + b0v.w + bb, 0.f);
        S1.x = fmaxf(a1.x + b1v.x + bb, 0.f); S1.y = fmaxf(a1.y + b1v.y + bb, 0.f);
        S1.z = fmaxf(a1.z + b1v.z + bb, 0.f); S1.w = fmaxf(a1.w + b1v.w + bb, 0.f);
        *(float4*)&h1Tf[o * 12]     = S0;
        *(float4*)&h1Tf[o * 12 + 4] = S1;
    }
    if (tid >= 256 && tid < 256 + RPB) {
        int r = tid - 256;
        float s = cst[0];
#pragma unroll
        for (int w = 0; w < 8; w++) s += redbuf[w][r];
        scin_s[r] = s;
    }
    __syncthreads();

    // ---- phase 4: layer2 FMA (256 -> 128), o-pair tiles, split-K x4 ----
    {
        int p = tid & 63, h = (tid >> 6) & 1, cg = tid >> 7;
        int c0 = cg << 6;
        float4 A0 = make_float4(0.f, 0.f, 0.f, 0.f);
        float4 A1 = A0;
#pragma unroll 4
        for (int cc = 0; cc < 64; cc++) {
            int c = c0 + cc;
            float2 wv = *(const float2*)&dW2[c * 128 + 2 * p];
            float4 iv = *(const float4*)&h1Tf[c * 12 + 4 * h];
            A0.x += iv.x * wv.x; A0.y += iv.y * wv.x; A0.z += iv.z * wv.x; A0.w += iv.w * wv.x;
            A1.x += iv.x * wv.y; A1.y += iv.y * wv.y; A1.z += iv.z * wv.y; A1.w += iv.w * wv.y;
        }
        pbuf4[tid * 2]     = A0;
        pbuf4[tid * 2 + 1] = A1;
    }
    __syncthreads();

    // ---- phase 5: layer2 combine + relu -> h2T (aliased over inT) ----
    if (tid < 128) {
        int o = tid;
        float bb = db2[o];
        float sx0 = bb, sy0 = bb, sz0 = bb, sw0 = bb;
        float sx1 = bb, sy1 = bb, sz1 = bb, sw1 = bb;
#pragma unroll
        for (int cg = 0; cg < 4; cg++) {
            float4 p0 = pbuf4[cg * 256 + o];
            float4 p1 = pbuf4[cg * 256 + 128 + o];
            sx0 += p0.x; sy0 += p0.y; sz0 += p0.z; sw0 += p0.w;
            sx1 += p1.x; sy1 += p1.y; sz1 += p1.z; sw1 += p1.w;
        }
        float4 S0, S1;
        S0.x = fmaxf(sx0, 0.f); S0.y = fmaxf(sy0, 0.f);
        S0.z = fmaxf(sz0, 0.f); S0.w = fmaxf(sw0, 0.f);
        S1.x = fmaxf(sx1, 0.f); S1.y = fmaxf(sy1, 0.f);
        S1.z = fmaxf(sz1, 0.f); S1.w = fmaxf(sw1, 0.f);
        *(float4*)&h2Tf[o * 12]     = S0;
        *(float4*)&h2Tf[o * 12 + 4] = S1;
    }
    __syncthreads();

    // ---- phase 6: layer3 FMA (128 -> 64), o-pair tiles, split-K x8 ----
    {
        int cg = tid >> 6, lane = tid & 63;
        int p = lane & 31, h = lane >> 5;
        int c0 = cg << 4;
        float4 A0 = make_float4(0.f, 0.f, 0.f, 0.f);
        float4 A1 = A0;
#pragma unroll 8
        for (int cc = 0; cc < 16; cc++) {
            int c = c0 + cc;
            float2 wv = *(const float2*)&dW3[c * 64 + 2 * p];
            float4 iv = *(const float4*)&h2Tf[c * 12 + 4 * h];
            A0.x += iv.x * wv.x; A0.y += iv.y * wv.x; A0.z += iv.z * wv.x; A0.w += iv.w * wv.x;
            A1.x += iv.x * wv.y; A1.y += iv.y * wv.y; A1.z += iv.z * wv.y; A1.w += iv.w * wv.y;
        }
        pbuf4[tid * 2]     = A0;
        pbuf4[tid * 2 + 1] = A1;
    }
    __syncthreads();

    // ---- phase 7: combine L3 + layer4 (64 -> 1) + final + sigmoid ----
    if (tid < 64) {
        int o = tid;
        float4 S0 = make_float4(0.f, 0.f, 0.f, 0.f);
        float4 S1 = S0;
#pragma unroll
        for (int cg = 0; cg < 8; cg++) {
            float4 p0 = pbuf4[cg * 128 + o];
            float4 p1 = pbuf4[cg * 128 + 64 + o];
            S0.x += p0.x; S0.y += p0.y; S0.z += p0.z; S0.w += p0.w;
            S1.x += p1.x; S1.y += p1.y; S1.z += p1.z; S1.w += p1.w;
        }
        float b3 = db3[o], w4 = dW4[o];
        S0.x = fmaxf(S0.x + b3, 0.f) * w4; S0.y = fmaxf(S0.y + b3, 0.f) * w4;
        S0.z = fmaxf(S0.z + b3, 0.f) * w4; S0.w = fmaxf(S0.w + b3, 0.f) * w4;
        S1.x = fmaxf(S1.x + b3, 0.f) * w4; S1.y = fmaxf(S1.y + b3, 0.f) * w4;
        S1.z = fmaxf(S1.z + b3, 0.f) * w4; S1.w = fmaxf(S1.w + b3, 0.f) * w4;
#pragma unroll
        for (int off = 1; off < 64; off <<= 1) {
            S0.x += __shfl_xor(S0.x, off, 64); S0.y += __shfl_xor(S0.y, off, 64);
            S0.z += __shfl_xor(S0.z, off, 64); S0.w += __shfl_xor(S0.w, off, 64);
            S1.x += __shfl_xor(S1.x, off, 64); S1.y += __shfl_xor(S1.y, off, 64);
            S1.z += __shfl_xor(S1.z, off, 64); S1.w += __shfl_xor(S1.w, off, 64);
        }
        if (tid == 0) {
            float sv[8] = { S0.x, S0.y, S0.z, S0.w, S1.x, S1.y, S1.z, S1.w };
            float bb = db4[0], cb = clb[0];
#pragma unroll
            for (int r = 0; r < RPB; r++) {
                float dense = fmaxf(sv[r] + bb, 0.f);
                float cin = fmaxf(scin_s[r] + cb, 0.f);
                float x = lin_s[r] + cin + dense;
                out[b0r + r] = 1.f / (1.f + expf(-x));
            }
        }
    }
}

extern "C" void kernel_launch(void* const* d_in, const int* in_sizes, int n_in,
                              void* d_out, int out_size, void* d_ws, size_t ws_size,
                              hipStream_t stream) {
    const float* inputs = (const float*)d_in[0];
    const float* tables = (const float*)d_in[1];
    const float* lW     = (const float*)d_in[2];
    const float* lb     = (const float*)d_in[3];
    const float* W0     = (const float*)d_in[4];
    const float* b0     = (const float*)d_in[5];
    const float* W1c    = (const float*)d_in[6];
    const float* b1c    = (const float*)d_in[7];
    const float* clw    = (const float*)d_in[8];
    const float* clb    = (const float*)d_in[9];
    const float* dW1    = (const float*)d_in[10];
    const float* db1    = (const float*)d_in[11];
    const float* dW2    = (const float*)d_in[12];
    const float* db2    = (const float*)d_in[13];
    const float* dW3    = (const float*)d_in[14];
    const float* db3    = (const float*)d_in[15];
    const float* dW4    = (const float*)d_in[16];
    const float* db4    = (const float*)d_in[17];

    float* ws   = (float*)d_ws;
    float* Gst  = ws + OFF_GST;
    float* cst  = ws + OFF_CST;
    float* c2j  = ws + OFF_C2J;

    k_pre<<<28, 256, 0, stream>>>(W0, W1c, b0, b1c, clw, Gst, cst, c2j);
    k_main<<<B / RPB, TPB, 0, stream>>>(inputs, tables, lW, lb, Gst, c2j, cst,
                                        dW1, db1, dW2, db2, dW3, db3, dW4, db4, clb,
                                        (float*)d_out);
}